// Round 3
// baseline (156.933 us; speedup 1.0000x reference)
//
#include <hip/hip_runtime.h>

// B=2, N=96, D=64, H=4, DK=16
#define ELEM_B 589824    // 9216*64 floats per batch per tensor
#define TENS   1179648   // 2*ELEM_B floats per projected tensor
#define T_ROWS 18432     // total rows

// ---------------------------------------------------------------------------
// 64-row x 64-col projection tile: dst = src @ W^T + b. 256 threads:
// c = t&63, rg = t>>6 owns 16 rows. W staged pitch-68 (conflict-free b128).
// ---------------------------------------------------------------------------
__device__ __forceinline__ void proj_tile64(
    const float* __restrict__ src, const float* __restrict__ w,
    const float* __restrict__ bias, float* __restrict__ dst,
    int row0, int t, float* sw, float* srow, float* sb)
{
#pragma unroll
    for (int j = 0; j < 4; ++j) {           // 1024 float4 slots of W
        const int s = t + j * 256;
        const int c = s >> 4, k4 = s & 15;
        *(float4*)&sw[c * 68 + k4 * 4] = *(const float4*)(w + s * 4);
    }
#pragma unroll
    for (int j = 0; j < 4; ++j) {           // 1024 float4 slots of 64 src rows
        const int s = t + j * 256;
        *(float4*)&srow[s * 4] = *(const float4*)(src + row0 * 64 + s * 4);
    }
    if (t < 64) sb[t] = bias[t];
    __syncthreads();

    const int c = t & 63, rg = t >> 6;
    float acc[16];
#pragma unroll
    for (int r = 0; r < 16; ++r) acc[r] = sb[c];
#pragma unroll
    for (int k4 = 0; k4 < 16; ++k4) {
        const float4 w4 = *(const float4*)&sw[c * 68 + k4 * 4];
#pragma unroll
        for (int r = 0; r < 16; ++r) {
            const float4 s4 = *(const float4*)&srow[(rg * 16 + r) * 64 + k4 * 4];
            acc[r] = fmaf(s4.x, w4.x, acc[r]);
            acc[r] = fmaf(s4.y, w4.y, acc[r]);
            acc[r] = fmaf(s4.z, w4.z, acc[r]);
            acc[r] = fmaf(s4.w, w4.w, acc[r]);
        }
    }
#pragma unroll
    for (int r = 0; r < 16; ++r)
        dst[(row0 + rg * 16 + r) * 64 + c] = acc[r];
}

__global__ __launch_bounds__(256) void proj4_kernel(
    const float* __restrict__ state,
    const float* __restrict__ w0, const float* __restrict__ b0,
    const float* __restrict__ w1, const float* __restrict__ b1,
    const float* __restrict__ w2, const float* __restrict__ b2,
    const float* __restrict__ w3, const float* __restrict__ b3,
    float* __restrict__ o0, float* __restrict__ o1,
    float* __restrict__ o2, float* __restrict__ o3)
{
    __shared__ float sw[64 * 68];
    __shared__ float srow[64 * 64];
    __shared__ float sb[64];
    const int mat  = blockIdx.x & 3;
    const int row0 = (blockIdx.x >> 2) * 64;
    const float* w = (mat == 0) ? w0 : (mat == 1) ? w1 : (mat == 2) ? w2 : w3;
    const float* b = (mat == 0) ? b0 : (mat == 1) ? b1 : (mat == 2) ? b2 : b3;
    float* o       = (mat == 0) ? o0 : (mat == 1) ? o1 : (mat == 2) ? o2 : o3;
    proj_tile64(state, w, b, o, row0, threadIdx.x, sw, srow, sb);
}

__global__ __launch_bounds__(256) void proj1_kernel(
    const float* __restrict__ src, const float* __restrict__ w,
    const float* __restrict__ b, float* __restrict__ dst)
{
    __shared__ float sw[64 * 68];
    __shared__ float srow[64 * 64];
    __shared__ float sb[64];
    proj_tile64(src, w, b, dst, blockIdx.x * 64, threadIdx.x, sw, srow, sb);
}

// ---------------------------------------------------------------------------
// Scores: block per (bh, a); 384 threads = 96 y x 4 xg; writes
// P[bh, x, a, y] = exp(S/4). No max-subtract: |S| << 1 by construction.
// ---------------------------------------------------------------------------
__global__ __launch_bounds__(384) void scores_kernel(
    const float* __restrict__ lk, const float* __restrict__ rk,
    float* __restrict__ P)
{
    __shared__ float lks[96][16];
    const int bid = blockIdx.x;
    const int a  = bid % 96;
    const int bh = bid / 96;             // b*4 + h
    const int b  = bh >> 2, h = bh & 3;
    const int t  = threadIdx.x;
    const int base = b * ELEM_B + h * 16;

    {   // stage lk[x=0..95][16]
        const int row = t >> 2, q = t & 3;
        *(float4*)&lks[row][q * 4] =
            *(const float4*)(lk + base + (row * 96 + a) * 64 + q * 4);
    }
    const int y = t % 96, xg = t / 96;
    const float4* rkp = (const float4*)(rk + base + (a * 96 + y) * 64);
    const float4 r0 = rkp[0], r1 = rkp[1], r2 = rkp[2], r3 = rkp[3];
    __syncthreads();

    float* Pout = P + (size_t)(bh * 96) * 9216 + a * 96 + y;
#pragma unroll 4
    for (int i = 0; i < 24; ++i) {
        const int x = xg * 24 + i;
        const float4* lp = (const float4*)lks[x];
        const float4 l0 = lp[0], l1 = lp[1], l2 = lp[2], l3 = lp[3];
        float s = l0.x * r0.x;
        s = fmaf(l0.y, r0.y, s); s = fmaf(l0.z, r0.z, s); s = fmaf(l0.w, r0.w, s);
        s = fmaf(l1.x, r1.x, s); s = fmaf(l1.y, r1.y, s); s = fmaf(l1.z, r1.z, s);
        s = fmaf(l1.w, r1.w, s); s = fmaf(l2.x, r2.x, s); s = fmaf(l2.y, r2.y, s);
        s = fmaf(l2.z, r2.z, s); s = fmaf(l2.w, r2.w, s); s = fmaf(l3.x, r3.x, s);
        s = fmaf(l3.y, r3.y, s); s = fmaf(l3.z, r3.z, s); s = fmaf(l3.w, r3.w, s);
        Pout[(size_t)x * 9216] = __expf(s * 0.25f);
    }
}

// ---------------------------------------------------------------------------
// Contraction v3 (barrier-free streaming):
// O[x,y,d] = (sum_a P*lv*rv) / (sum_a P).
// Block per (bh, xt of 4, yq of 24): 768 blocks, 384 threads.
// Thread = (dq = t&3, y = (t>>2)%24, xi = (t>>2)/24). Streams rv (float4) and
// P (scalar, L1-broadcast across 4 dq lanes) from global; lv staged in LDS
// once. Zero barriers in the a-loop -> deep software pipelining.
// ---------------------------------------------------------------------------
__global__ __launch_bounds__(384) void contract_kernel(
    const float* __restrict__ lv, const float* __restrict__ rv,
    const float* __restrict__ P, float* __restrict__ xb)
{
    __shared__ float lvs[4][96][16];
    const int bid = blockIdx.x;
    const int yq = bid & 3;
    const int xt = (bid >> 2) % 24;
    const int bh = bid / 96;
    const int b = bh >> 2, h = bh & 3;
    const int x0 = xt * 4, y0 = yq * 24;
    const int t = threadIdx.x;
    const int base = b * ELEM_B + h * 16;

    {   // stage lv[4][96][16]: 1536 float4 slots, 4 per thread
        const int aa = t >> 2, q = t & 3;
#pragma unroll
        for (int j = 0; j < 4; ++j)
            *(float4*)&lvs[j][aa][q * 4] =
                *(const float4*)(lv + base + ((x0 + j) * 96 + aa) * 64 + q * 4);
    }
    __syncthreads();

    const int dq = t & 3;
    const int q2 = t >> 2;
    const int y  = q2 % 24;
    const int xi = q2 / 24;
    const int yy = y0 + y;

    const float* rvp = rv + base + yy * 64 + dq * 4;                 // += a*6144
    const float* Pp  = P + (size_t)(bh * 96) * 9216 + (size_t)(x0 + xi) * 9216 + yy;  // += a*96

    float4 acc = make_float4(0.f, 0.f, 0.f, 0.f);
    float den = 0.f;
#pragma unroll 8
    for (int a = 0; a < 96; ++a) {
        const float4 r4 = *(const float4*)(rvp + a * 6144);
        const float  p  = Pp[a * 96];
        const float4 l4 = *(const float4*)&lvs[xi][a][dq * 4];
        den += p;
        acc.x = fmaf(p * l4.x, r4.x, acc.x);
        acc.y = fmaf(p * l4.y, r4.y, acc.y);
        acc.z = fmaf(p * l4.z, r4.z, acc.z);
        acc.w = fmaf(p * l4.w, r4.w, acc.w);
    }

    const float inv = 1.0f / den;
    float4 o;
    o.x = acc.x * inv; o.y = acc.y * inv; o.z = acc.z * inv; o.w = acc.w * inv;
    *(float4*)(xb + base + ((x0 + xi) * 96 + yy) * 64 + dq * 4) = o;
}

extern "C" void kernel_launch(void* const* d_in, const int* in_sizes, int n_in,
                              void* d_out, int out_size, void* d_ws, size_t ws_size,
                              hipStream_t stream)
{
    const float* state = (const float*)d_in[0];
    const float* w_lk  = (const float*)d_in[1];
    const float* b_lk  = (const float*)d_in[2];
    const float* w_rk  = (const float*)d_in[3];
    const float* b_rk  = (const float*)d_in[4];
    const float* w_lv  = (const float*)d_in[5];
    const float* b_lv  = (const float*)d_in[6];
    const float* w_rv  = (const float*)d_in[7];
    const float* b_rv  = (const float*)d_in[8];
    const float* w_out = (const float*)d_in[9];
    const float* b_out = (const float*)d_in[10];
    float* out = (float*)d_out;

    float* ws = (float*)d_ws;
    float* lk = ws;
    float* rk = ws + (size_t)TENS;
    float* lv = ws + (size_t)2 * TENS;
    float* rv = ws + (size_t)3 * TENS;
    float* xb = ws + (size_t)4 * TENS;
    float* P  = ws + (size_t)5 * TENS;   // 8*96*9216 floats = 28.3 MB

    proj4_kernel<<<4 * (T_ROWS / 64), 256, 0, stream>>>(
        state, w_lk, b_lk, w_rk, b_rk, w_lv, b_lv, w_rv, b_rv, lk, rk, lv, rv);
    scores_kernel<<<8 * 96, 384, 0, stream>>>(lk, rk, P);
    contract_kernel<<<768, 384, 0, stream>>>(lv, rv, P, xb);
    proj1_kernel<<<T_ROWS / 64, 256, 0, stream>>>(xb, w_out, b_out, out);
}